// Round 9
// baseline (297.832 us; speedup 1.0000x reference)
//
#include <hip/hip_runtime.h>

// DMDNet: 8 sequential complex GEMM steps [256 x 8192] @ [8192 x 1024] in bf16 MFMA.
// B=256, L=8, M=1024, P=8 (hardcoded per setup_inputs).
// Round 9: 32x32x16 MFMA (2x FLOP per LDS byte and per MFMA-issue slot) with
// 64x32 wave tiles -> per-chunk MFMA(1024cyc) >> LDS(500)/feed(571): compute-
// dominant so phase serialization hides under the MFMA pipe. Block 512thr/8w,
// tile 128x128, K=512, k-octet-major LDS layouts (conflict-free, linear
// global_load_lds). Slices stay 16. XCD pinning kept.
//
// Layouts (shorts):
//  S3[slot 8][kc 32][oct 4][b 256][8]    (k = kc*32 + oct*8 + j)
//  W3[p 8][kc 32][oct 4][m 1024][8]      (W3[..n..][m] = Ag[p][m][n], Ag[p]=A[(8-p)&7])
//  Pp[slice 16][rowt 2][colt 8][tid 512][64]  (slice = p*2+ks)

#define LW 8

typedef __attribute__((ext_vector_type(8))) short   short8;
typedef __attribute__((ext_vector_type(8))) __bf16  bf16x8;
typedef __attribute__((ext_vector_type(16))) float  f32x16;
typedef __attribute__((ext_vector_type(4))) float   f4;
typedef const __attribute__((address_space(1))) void gvoid_t;
typedef __attribute__((address_space(3))) void lvoid_t;

static __device__ __forceinline__ short f2bf(float f) {
  unsigned u = __builtin_bit_cast(unsigned, f);
  u += 0x7FFFu + ((u >> 16) & 1u);
  return (short)(u >> 16);
}
static __device__ __forceinline__ float bf2f(short s) {
  unsigned u = ((unsigned)(unsigned short)s) << 16;
  return __builtin_bit_cast(float, u);
}
static __device__ __forceinline__ f32x16 mfma32(short8 a, short8 b, f32x16 c) {
  return __builtin_amdgcn_mfma_f32_32x32x16_bf16(
      __builtin_bit_cast(bf16x8, a), __builtin_bit_cast(bf16x8, b), c, 0, 0, 0);
}

// S3 init: S3[s][kc][oct][b][j] = bf16(x[b][s][kc*32+oct*8+j]); imag = 0.
__global__ __launch_bounds__(256) void prep_s(const float* __restrict__ x,
                                              short* __restrict__ Sr3,
                                              short* __restrict__ Si3) {
  const int tg = blockIdx.x * 256 + threadIdx.x;    // 262144
  const int oct = tg & 3, b_lo = (tg >> 2) & 15, b_hi = (tg >> 6) & 15;
  const int kc = (tg >> 10) & 31, s = tg >> 15;
  const int b = (b_hi << 4) + b_lo;
  const float* xp = x + ((size_t)(b * 8 + s) << 10) + (kc << 5) + (oct << 3);
  f4 x0 = *(const f4*)xp, x1 = *(const f4*)(xp + 4);
  short8 v;
#pragma unroll
  for (int j = 0; j < 4; ++j) { v[j] = f2bf(x0[j]); v[j + 4] = f2bf(x1[j]); }
  const size_t dst = ((size_t)(((s * 32 + kc) << 2) + oct) << 11) + (b << 3);
  *(short8*)(Sr3 + dst) = v;
  short8 z = {0, 0, 0, 0, 0, 0, 0, 0};
  *(short8*)(Si3 + dst) = z;
}

// W3[p][kc][oct][m][j] = Ag[p][m][kc*32+oct*8+j], Ag[p] = A[(8-p)&7].
__global__ __launch_bounds__(256) void prep_w(const float* __restrict__ Ar,
                                              const float* __restrict__ Ai,
                                              short* __restrict__ Wr3,
                                              short* __restrict__ Wi3) {
  const int tg = blockIdx.x * 256 + threadIdx.x;    // 1048576
  const int oct = tg & 3, m_lo = (tg >> 2) & 15, m_hi = (tg >> 6) & 63;
  const int kc = (tg >> 12) & 31, p = tg >> 17;
  const int m = (m_hi << 4) + m_lo;
  const int q = (LW - p) & 7;
  const size_t src = ((size_t)((q << 10) + m) << 10) + (kc << 5) + (oct << 3);
  f4 r0 = *(const f4*)(Ar + src), r1 = *(const f4*)(Ar + src + 4);
  f4 i0 = *(const f4*)(Ai + src), i1 = *(const f4*)(Ai + src + 4);
  short8 vr, vi;
#pragma unroll
  for (int j = 0; j < 4; ++j) {
    vr[j] = f2bf(r0[j]); vr[j + 4] = f2bf(r1[j]);
    vi[j] = f2bf(i0[j]); vi[j + 4] = f2bf(i1[j]);
  }
  const size_t dst = ((size_t)(((p * 32 + kc) << 2) + oct) << 13) + (m << 3);
  *(short8*)(Wr3 + dst) = vr;
  *(short8*)(Wi3 + dst) = vi;
}

// ---- gemm: grid 256 (p=bid&7 XCD-pinned, ks2, rowt2, colt8), 512 thr = 8 waves ----
// Block tile 128x128, wave tile 64x32 (rf2 of 32x32-mfma), K=512 = 16 chunks of 32.

#define STAGE(kcg_, buf_) do {                                                   \
    const size_t ka_ = (size_t)(kcg_) << 13;                                     \
    const size_t kb_ = (size_t)(kcg_) << 15;                                     \
    __builtin_amdgcn_global_load_lds((gvoid_t*)(srcAr + ka_),                    \
        (lvoid_t*)&ldsA[buf_][dstA], 16, 0, 0);                                  \
    __builtin_amdgcn_global_load_lds((gvoid_t*)(srcAi + ka_),                    \
        (lvoid_t*)&ldsA[buf_][dstA + 4096], 16, 0, 0);                           \
    __builtin_amdgcn_global_load_lds((gvoid_t*)(srcBr + kb_),                    \
        (lvoid_t*)&ldsB[buf_][dstB], 16, 0, 0);                                  \
    __builtin_amdgcn_global_load_lds((gvoid_t*)(srcBi + kb_),                    \
        (lvoid_t*)&ldsB[buf_][dstB + 4096], 16, 0, 0);                           \
  } while (0)

#define COMPUTE(buf_) do {                                                       \
    _Pragma("unroll")                                                            \
    for (int k2_ = 0; k2_ < 2; ++k2_) {                                          \
      const int ob_ = ((k2_ << 1) + h) << 10;                                    \
      const short* A_ = &ldsA[buf_][ob_];                                        \
      const short* B_ = &ldsB[buf_][ob_];                                        \
      short8 aR0 = *(const short8*)(A_ + arow8);                                 \
      short8 aR1 = *(const short8*)(A_ + arow8 + 256);                           \
      short8 aI0 = *(const short8*)(A_ + 4096 + arow8);                          \
      short8 aI1 = *(const short8*)(A_ + 4096 + arow8 + 256);                    \
      short8 bR  = *(const short8*)(B_ + bcol8);                                 \
      short8 bI  = *(const short8*)(B_ + 4096 + bcol8);                          \
      short8 n0_ = aI0 ^ SGN, n1_ = aI1 ^ SGN;                                   \
      accR0 = mfma32(aR0, bR, accR0);                                            \
      accR0 = mfma32(n0_, bI, accR0);                                            \
      accI0 = mfma32(aR0, bI, accI0);                                            \
      accI0 = mfma32(aI0, bR, accI0);                                            \
      accR1 = mfma32(aR1, bR, accR1);                                            \
      accR1 = mfma32(n1_, bI, accR1);                                            \
      accI1 = mfma32(aR1, bI, accI1);                                            \
      accI1 = mfma32(aI1, bR, accI1);                                            \
    }                                                                            \
  } while (0)

__global__ __launch_bounds__(512, 2) void gemm_step(const short* __restrict__ Sr3,
                                                    const short* __restrict__ Si3,
                                                    const short* __restrict__ Wr3,
                                                    const short* __restrict__ Wi3,
                                                    short* __restrict__ Pp,
                                                    int t) {
  __shared__ short ldsA[2][8192];    // [buf][cx2][oct4][row128][8]  32 KB
  __shared__ short ldsB[2][8192];    // [buf][cx2][oct4][col128][8]  32 KB

  const int bid   = blockIdx.x;
  const int p     = bid & 7;                // XCD-pinned
  const int inner = bid >> 3;               // 0..31
  const int colt  = inner & 7;
  const int rowt  = (inner >> 3) & 1;
  const int ks    = inner >> 4;             // 0/1
  const int s     = (p + t) & 7;
  const int kcg0  = ks << 4;

  const int tid = threadIdx.x, lane = tid & 63, w = tid >> 6;
  const int rw = w >> 2, cw = w & 3;
  const int l31 = lane & 31, h = lane >> 5;

  // staging addresses (thread -> one 16B granule per array)
  const int oct_t = tid >> 7, idx_t = tid & 127;
  const short* srcAr = Sr3 + ((size_t)s << 18) + (((oct_t << 8) + (rowt << 7) + idx_t) << 3);
  const short* srcAi = Si3 + ((size_t)s << 18) + (((oct_t << 8) + (rowt << 7) + idx_t) << 3);
  const short* srcBr = Wr3 + ((size_t)p << 20) + (((oct_t << 10) + (colt << 7) + idx_t) << 3);
  const short* srcBi = Wi3 + ((size_t)p << 20) + (((oct_t << 10) + (colt << 7) + idx_t) << 3);
  const int dstA = (oct_t << 10) + (idx_t << 3);
  const int dstB = dstA;

  // LDS read offsets (shorts)
  const int arow8 = ((rw << 6) + l31) << 3;        // rf adds 256
  const int bcol8 = ((cw << 5) + l31) << 3;

  f32x16 accR0, accR1, accI0, accI1;
#pragma unroll
  for (int e = 0; e < 16; ++e) { accR0[e] = 0.f; accR1[e] = 0.f; accI0[e] = 0.f; accI1[e] = 0.f; }

  const short8 SGN = {(short)0x8000, (short)0x8000, (short)0x8000, (short)0x8000,
                      (short)0x8000, (short)0x8000, (short)0x8000, (short)0x8000};

  STAGE(kcg0, 0);
#pragma unroll
  for (int kc = 0; kc < 16; ++kc) {
    const int buf = kc & 1;
    __syncthreads();                  // stage(kc) landed; prev compute done
    if (kc < 15) STAGE(kcg0 + kc + 1, buf ^ 1);
    COMPUTE(buf);
  }

  // packed bf16 partials: 64 shorts/thread; octet o8 = rf*4 + RI*2 + hi
  short* op = Pp + ((((size_t)(((p << 1) + ks) * 2 + rowt) << 3) + colt) * 512 + tid) * 64;
#pragma unroll
  for (int rf = 0; rf < 2; ++rf)
#pragma unroll
    for (int RI = 0; RI < 2; ++RI)
#pragma unroll
      for (int hi = 0; hi < 2; ++hi) {
        short8 sv;
#pragma unroll
        for (int jj = 0; jj < 8; ++jj) {
          const int reg = (hi << 3) + jj;
          float v;
          if (rf == 0) v = (RI == 0) ? accR0[reg] : accI0[reg];
          else         v = (RI == 0) ? accR1[reg] : accI1[reg];
          sv[jj] = f2bf(v);
        }
        *(short8*)(op + (((rf << 2) + (RI << 1) + hi) << 3)) = sv;
      }
}

// Reduce 16 slices; write out (f32) + new state slot t in S3 layout.
__global__ __launch_bounds__(256) void reduce_step(const short* __restrict__ Pp,
                                                   short* __restrict__ Sr3,
                                                   short* __restrict__ Si3,
                                                   float* __restrict__ out,
                                                   int t) {
  const int r = blockIdx.x * 256 + threadIdx.x;   // 65536
  const int tidg = r & 511, o8 = (r >> 9) & 7, colt = (r >> 12) & 7, rowt = (r >> 15) & 1;

  float sum[8] = {0.f, 0.f, 0.f, 0.f, 0.f, 0.f, 0.f, 0.f};
#pragma unroll
  for (int sl = 0; sl < 16; ++sl) {
    const short8 v = *(const short8*)(
        Pp + ((((size_t)((sl * 2 + rowt) << 3) + colt) * 512 + tidg) * 64) + (o8 << 3));
#pragma unroll
    for (int jj = 0; jj < 8; ++jj) sum[jj] += bf2f(v[jj]);
  }

  const int rf = o8 >> 2, RI = (o8 >> 1) & 1, hi = o8 & 1;
  const int lane = tidg & 63, w = tidg >> 6;
  const int rw = w >> 2, cw = w & 3;
  const int col   = (colt << 7) + (cw << 5) + (lane & 31);
  const int rbase = (rowt << 7) + (rw << 6) + (rf << 5) + ((lane >> 5) << 2) + (hi << 4);
  const size_t sb = ((size_t)(((t * 32 + (col >> 5)) << 2) + ((col >> 3) & 3)) << 11) + (col & 7);

  if (RI == 0) {
#pragma unroll
    for (int jj = 0; jj < 8; ++jj) {
      const int row = rbase + (jj & 3) + ((jj >> 2) << 3);
      out[((size_t)((row << 3) + t) << 10) + col] = sum[jj];
      Sr3[sb + (row << 3)] = f2bf(sum[jj]);
    }
  } else {
#pragma unroll
    for (int jj = 0; jj < 8; ++jj) {
      const int row = rbase + (jj & 3) + ((jj >> 2) << 3);
      Si3[sb + (row << 3)] = f2bf(sum[jj]);
    }
  }
}

extern "C" void kernel_launch(void* const* d_in, const int* in_sizes, int n_in,
                              void* d_out, int out_size, void* d_ws, size_t ws_size,
                              hipStream_t stream) {
  const float* x  = (const float*)d_in[0];
  const float* Ar = (const float*)d_in[1];
  const float* Ai = (const float*)d_in[2];
  // d_in[3] = predict_length == 8 per setup_inputs(); hardcoded.
  float* out = (float*)d_out;

  char* ws = (char*)d_ws;
  if (ws_size < (56u << 20)) return;
  short* Sr3 = (short*)(ws);                     //  4 MiB  [8][32][4][256][8]
  short* Si3 = (short*)(ws + (4u  << 20));       //  4 MiB
  short* Wr3 = (short*)(ws + (8u  << 20));       // 16 MiB  [8][32][4][1024][8]
  short* Wi3 = (short*)(ws + (24u << 20));       // 16 MiB
  short* Pp  = (short*)(ws + (40u << 20));       // 16 MiB  [16][2][8][512][64]

  prep_w<<<dim3(4096), dim3(256), 0, stream>>>(Ar, Ai, Wr3, Wi3);
  prep_s<<<dim3(1024), dim3(256), 0, stream>>>(x, Sr3, Si3);
  for (int t = 0; t < 8; ++t) {
    gemm_step<<<dim3(256), dim3(512), 0, stream>>>(Sr3, Si3, Wr3, Wi3, Pp, t);
    reduce_step<<<dim3(256), dim3(256), 0, stream>>>(Pp, Sr3, Si3, out, t);
  }
}